// Round 9
// baseline (299.110 us; speedup 1.0000x reference)
//
#include <hip/hip_runtime.h>
#include <hip/hip_fp16.h>
#include <cstddef>

// ---------------------------------------------------------------------------
// CrossAttention, f16 MFMA, round 17.
//   B=2, Sq=Sk=2048, D=1024, H=16, Dh=64
// r16 post-mortem: attn tile period 3500 cyc vs ~900 issue -> bound by (a)
// DS pipe: 80 b128/tile/block x 12cyc x 2 blocks = 1920 cyc/tile-period,
// 4x LDS read amplification (4 qb-waves re-read same K band); (b) per-tile
// barrier drains vmcnt(0) -> prefetch latency lands in every tile.
// r17: ZERO-barrier, ZERO-LDS main loop. K/V A-frags loaded directly from
// global (L1/L2-resident; redundant reads across waves are L1 hits). LDS
// only in epilogue. V-load latency hides under QK+exp+pack (vmcnt(4) before
// QK). Regs ~122 -> launch_bounds(512,4) cap 128 (WRITE_SIZE = spill gate).
// gemm_core: r16 global_load_lds m97 structure (kept). XCD swizzles kept.
// Layouts (32x32x16): A/B [idx=lane&31][k=(lane>>5)*8+j];
//   C/D col=lane&31, row=(reg&3)+8*(reg>>2)+4*(lane>>5)  [m74/m101].
// P repack: P0=pk(s0,s1) P1=pk(s2,s3) P2=pk(s4,s5) P3=pk(s6,s7);
//   swap(P0,P2), swap(P1,P3) -> B-frag words [P0,P1,P2,P3]. (r13-verified)
// ---------------------------------------------------------------------------

#define B_   2
#define S_   2048
#define D_   1024
#define H_   16
#define DH_  64

typedef _Float16 half8 __attribute__((ext_vector_type(8)));
typedef _Float16 half4 __attribute__((ext_vector_type(4)));
typedef _Float16 half2v __attribute__((ext_vector_type(2)));
typedef float floatx4 __attribute__((ext_vector_type(4)));
typedef float floatx16 __attribute__((ext_vector_type(16)));
typedef int intx4 __attribute__((ext_vector_type(4)));

#define MFMA32(a, b, c) __builtin_amdgcn_mfma_f32_16x16x32_f16((a), (b), (c), 0, 0, 0)
#define MFMA3216(a, b, c) __builtin_amdgcn_mfma_f32_32x32x16_f16((a), (b), (c), 0, 0, 0)

#if __has_builtin(__builtin_amdgcn_fdot2)
#define LP_FDOT2 1
#else
#define LP_FDOT2 0
#endif

#define GLD_AS(p) ((const __attribute__((address_space(1))) void*)(p))
#define LDS_AS(p) ((__attribute__((address_space(3))) void*)(p))

// exchange: newA = {A.lo32, B.lo32}, newB = {A.hi32, B.hi32}
__device__ __forceinline__ void half_swap(int& a, int& b, const int hi) {
#if __has_builtin(__builtin_amdgcn_permlane32_swap)
    (void)hi;
    auto r = __builtin_amdgcn_permlane32_swap(a, b, false, false);
    a = r[0]; b = r[1];
#else
    const int ax = __shfl_xor(a, 32, 64), bx = __shfl_xor(b, 32, 64);
    const int na = hi ? bx : a;
    b = hi ? b : ax;
    a = na;
#endif
}

// ---- fused: fp32->f16 cvt for q/k/v (z<3) + W transpose x4 (z==3) ----
__global__ __launch_bounds__(256) void prep(
    const float* __restrict__ q, const float* __restrict__ k,
    const float* __restrict__ v,
    __half* __restrict__ qf, __half* __restrict__ kf, __half* __restrict__ vf,
    const float* __restrict__ Wq, const float* __restrict__ Wk,
    const float* __restrict__ Wv, const float* __restrict__ Wo,
    __half* __restrict__ Wtq, __half* __restrict__ Wtk,
    __half* __restrict__ Wtv, __half* __restrict__ Wto)
{
    __shared__ __align__(16) __half T[64][72];
    const int tid = threadIdx.x;
    const int z = blockIdx.z;
    if (z < 3) {
        const float* srcs[3] = {q, k, v};
        __half* dsts[3] = {qf, kf, vf};
        const int i = blockIdx.x * 256 + tid;
        const float4* s = (const float4*)srcs[z];
        const float4 a = s[2 * i], b = s[2 * i + 1];
        half8 h;
        h[0] = (_Float16)a.x; h[1] = (_Float16)a.y; h[2] = (_Float16)a.z; h[3] = (_Float16)a.w;
        h[4] = (_Float16)b.x; h[5] = (_Float16)b.y; h[6] = (_Float16)b.z; h[7] = (_Float16)b.w;
        *(half8*)&dsts[z][(size_t)i * 8] = h;
        return;
    }
    if (blockIdx.x >= 256) return;
    const float* Ws[4] = {Wq, Wk, Wv, Wo};
    __half* Wts[4] = {Wtq, Wtk, Wtv, Wto};
    const int n0 = (blockIdx.x & 15) * 64, k0 = (blockIdx.x >> 4) * 64;
    for (int w = 0; w < 4; ++w) {
        const float* W = Ws[w];
        __half* Wt = Wts[w];
        #pragma unroll
        for (int p = 0; p < 4; ++p) {
            const int c = tid + p * 256;
            const int kr = c >> 4, nc = (c & 15) * 4;
            const float4 a = *(const float4*)&W[(size_t)(k0 + kr) * D_ + n0 + nc];
            T[nc + 0][kr] = __float2half(a.x);
            T[nc + 1][kr] = __float2half(a.y);
            T[nc + 2][kr] = __float2half(a.z);
            T[nc + 3][kr] = __float2half(a.w);
        }
        __syncthreads();
        #pragma unroll
        for (int p = 0; p < 2; ++p) {
            const int c = tid + p * 256;
            const int nr = c >> 3, kc = (c & 7) * 8;
            *(half8*)&Wt[(size_t)(n0 + nr) * D_ + k0 + kc] = *(const half8*)&T[nr][kc];
        }
        __syncthreads();
    }
}

// ---- 128x128 f16 GEMM core, m97-style global_load_lds staging (r16) ----
__device__ __forceinline__ void gemm_core(
    const __half* __restrict__ A, const __half* __restrict__ Bt,
    const float* __restrict__ bias, void* __restrict__ dst,
    const int mode, const float oscale, const int m0, const int n0)
{
    __shared__ __align__(16) char gsm[34816];
    __half* Asl = (__half*)gsm;            // [128][64] linear
    __half* Bsl = (__half*)(gsm + 16384);  // [128][64] linear

    const int tid = threadIdx.x;
    const int lane = tid & 63, wv = tid >> 6;
    const int quad = lane >> 4, lr = lane & 15;
    const int wm0 = (wv >> 1) * 64, wn0 = (wv & 1) * 64;

    floatx4 acc[4][4];
    #pragma unroll
    for (int i = 0; i < 4; ++i)
        #pragma unroll
        for (int j = 0; j < 4; ++j)
            acc[i][j] = (floatx4){0.f, 0.f, 0.f, 0.f};

    const int rowb = wv * 32 + (lane >> 3);
    const int colb = (lane & 7) * 8;
    const __half* gA = A  + (size_t)(m0 + rowb) * D_ + colb;
    const __half* gB = Bt + (size_t)(n0 + rowb) * D_ + colb;

    for (int k0 = 0; k0 < D_; k0 += 64) {
        __syncthreads();                  // prior compute's LDS reads done
        #pragma unroll
        for (int p = 0; p < 4; ++p) {
            __builtin_amdgcn_global_load_lds(
                GLD_AS(gA + (size_t)p * 8 * D_),
                LDS_AS(gsm + (wv * 4 + p) * 1024), 16, 0, 0);
            __builtin_amdgcn_global_load_lds(
                GLD_AS(gB + (size_t)p * 8 * D_),
                LDS_AS(gsm + 16384 + (wv * 4 + p) * 1024), 16, 0, 0);
        }
        gA += 64; gB += 64;
        __syncthreads();                  // staged tile visible (vmcnt drained)

        __builtin_amdgcn_s_setprio(1);
        #pragma unroll
        for (int ks = 0; ks < 2; ++ks) {
            const int ko = quad * 8 + ks * 32;
            half8 af[4], bf[4];
            #pragma unroll
            for (int i = 0; i < 4; ++i)
                af[i] = *(const half8*)&Asl[(wm0 + i * 16 + lr) * 64 + ko];
            #pragma unroll
            for (int j = 0; j < 4; ++j)
                bf[j] = *(const half8*)&Bsl[(wn0 + j * 16 + lr) * 64 + ko];
            #pragma unroll
            for (int i = 0; i < 4; ++i)
                #pragma unroll
                for (int j = 0; j < 4; ++j)
                    acc[i][j] = MFMA32(af[i], bf[j], acc[i][j]);
        }
        __builtin_amdgcn_s_setprio(0);
    }

    if (mode == 1) {
        float* out = (float*)dst;
        #pragma unroll
        for (int i = 0; i < 4; ++i) {
            #pragma unroll
            for (int j = 0; j < 4; ++j) {
                const int col = n0 + wn0 + j * 16 + lr;
                const float bval = bias[col];
                #pragma unroll
                for (int r = 0; r < 4; ++r) {
                    const int m = m0 + wm0 + i * 16 + quad * 4 + r;
                    out[(size_t)m * D_ + col] = acc[i][j][r] + bval;
                }
            }
        }
        return;
    }

    // ---- LDS transpose epilogue (modes 0 and 2) ----
    __syncthreads();                      // all waves' staging reads done
    __half (*Ct)[136] = (__half(*)[136])gsm;
    #pragma unroll
    for (int i = 0; i < 4; ++i) {
        #pragma unroll
        for (int j = 0; j < 4; ++j) {
            const int nl = wn0 + j * 16 + lr;
            const float bval = bias[n0 + nl];
            #pragma unroll
            for (int r = 0; r < 4; ++r) {
                const int ml = wm0 + i * 16 + quad * 4 + r;
                const _Float16 hv = (_Float16)((acc[i][j][r] + bval) * oscale);
                if (mode == 0) Ct[ml][nl] = hv;
                else           Ct[nl][ml] = hv;
            }
        }
    }
    __syncthreads();
    __half* oh = (__half*)dst;
    #pragma unroll
    for (int p = 0; p < 8; ++p) {
        const int row = (tid >> 4) + p * 16;
        const int cs  = (tid & 15) * 8;
        const half8 vls = *(const half8*)&Ct[row][cs];
        if (mode == 0) {
            const int m = m0 + row, col = n0 + cs;
            const int b = m >> 11, s = m & (S_ - 1);
            const int h = col >> 6, d = col & 63;
            *(half8*)&oh[(((size_t)(b * H_ + h) * S_ + s) << 6) + d] = vls;
        } else {
            const int col = n0 + row, m = m0 + cs;
            const int b = m >> 11, s = m & (S_ - 1);
            const int h = col >> 6, d = col & 63;
            *(half8*)&oh[((size_t)(b * H_ + h) * DH_ + d) * S_ + s] = vls;
        }
    }
}

// z=0: Q (scatter, *0.125*log2e for exp2 softmax), z=1: K, z=2: V (transposed)
// XCD swizzle: grid (8,32,3)=768 blocks, 96/XCD contiguous (bijective).
__global__ __launch_bounds__(256) void gemm_proj(
    const __half* __restrict__ qf, const __half* __restrict__ kf,
    const __half* __restrict__ vf,
    const __half* __restrict__ Wtq, const __half* __restrict__ Wtk,
    const __half* __restrict__ Wtv,
    const float* __restrict__ bq, const float* __restrict__ bk,
    const float* __restrict__ bv,
    __half* __restrict__ qhf, __half* __restrict__ khf, __half* __restrict__ vht)
{
    const int flat = blockIdx.x + (blockIdx.y << 3) + (blockIdx.z << 8);
    const int wid = (flat & 7) * 96 + (flat >> 3);
    const int z = wid >> 8;
    const int rem = wid & 255;
    const int m0 = (rem >> 3) * 128, n0 = (rem & 7) * 128;

    const __half* As[3] = {qf, kf, vf};
    const __half* Bts[3] = {Wtq, Wtk, Wtv};
    const float* bs[3] = {bq, bk, bv};
    __half* ds[3] = {qhf, khf, vht};
    gemm_core(As[z], Bts[z], bs[z], ds[z], z == 2 ? 2 : 0,
              z == 0 ? 0.1803368801111244f : 1.0f, m0, n0);
}

// XCD swizzle: grid (8,32)=256 blocks, 32/XCD contiguous.
__global__ __launch_bounds__(256) void gemm_final(
    const __half* __restrict__ attf, const __half* __restrict__ Wto,
    const float* __restrict__ bo, float* __restrict__ out)
{
    const int flat = blockIdx.x + (blockIdx.y << 3);
    const int wid = (flat & 7) * 32 + (flat >> 3);
    const int m0 = (wid >> 3) * 128, n0 = (wid & 7) * 128;
    gemm_core(attf, Wto, bo, out, 1, 1.0f, m0, n0);
}

// ---- flash attention r17: barrier-free, LDS-free main loop ----
// qhf/khf: [B,H,S,64] f16 (Q pre-scaled 0.125*log2e). vht: [B,H,64,S].
// Wave wv: kb=wv>>2 (k-band 32), qb=wv&3 (q-band 32 of 128). Per 64-k tile
// per wave: 4 K-frag + 4 V-frag global loads (L1/L2-hit; lane pairs =
// 32B segments) -> 4 QK MFMA -> 16 exp2 -> repack -> 4 PV MFMA -> 8 fdot2.
// No __syncthreads in the loop; LDS only for the epilogue k-band reduce.
// XCD swizzle: grid (16,32)=512 blocks, 64/XCD = 4 complete heads' K/V.
__global__ __launch_bounds__(512, 4) void attn_f16(
    const __half* __restrict__ qhf, const __half* __restrict__ khf,
    const __half* __restrict__ vht, __half* __restrict__ attf)
{
    __shared__ __align__(16) char smem[34816];

    const int tid = threadIdx.x;
    const int lane = tid & 63, wv = tid >> 6;
    const int l31 = lane & 31, hi = lane >> 5;
    const int kb = wv >> 2, qb = wv & 3;
    const int flat = blockIdx.x + (blockIdx.y << 4);
    const int wid = ((flat & 7) << 6) + (flat >> 3);
    const int bh = wid >> 4;
    const int q0 = (wid & 15) * 128;
    const size_t hbase = (size_t)bh * S_ * DH_;

    // ---- Q B-frags [idx=q=l31][k(d)=hi*8+j] per 16-d slice, from global ----
    half8 qB[4];
    #pragma unroll
    for (int ds = 0; ds < 4; ++ds)
        qB[ds] = *(const half8*)&qhf[hbase
            + (size_t)(q0 + qb * 32 + l31) * DH_ + ds * 16 + hi * 8];

    float lp0 = 0.f, lp1 = 0.f;
#if !LP_FDOT2
    float lp2 = 0.f, lp3 = 0.f;
#endif
    floatx16 O[2];
    #pragma unroll
    for (int i = 0; i < 16; ++i) { O[0][i] = 0.f; O[1][i] = 0.f; }

    // ---- per-wave direct A-frag pointers ----
    // K frag: row kb*32+l31 (+kt), col ds*16 + hi*8
    const __half* kp = khf + hbase + (size_t)(kb * 32 + l31) * DH_ + hi * 8;
    // V frag: row db*32+l31, col kt + kb*32 + ks*16 + hi*8
    const __half* vp = vht + hbase + (size_t)l31 * S_ + kb * 32 + hi * 8;

    const half2v one2 = {(_Float16)1.0f, (_Float16)1.0f};

    for (int kt = 0; kt < S_; kt += 64) {
        // ---- direct frag loads (K first; V latency hides under QK+exp) ----
        half8 kA[4], vA[4];
        #pragma unroll
        for (int ds = 0; ds < 4; ++ds)
            kA[ds] = *(const half8*)(kp + ds * 16);
        #pragma unroll
        for (int db = 0; db < 2; ++db)
            #pragma unroll
            for (int ks = 0; ks < 2; ++ks)
                vA[db * 2 + ks] = *(const half8*)(vp + (size_t)db * 32 * S_ + ks * 16);
        kp += 64 * DH_;
        vp += 64;

        // ---- S^T = K Q^T : 32k (band kb) x 32q (band qb), K-dim = d ----
        floatx16 s;
        #pragma unroll
        for (int i = 0; i < 16; ++i) s[i] = 0.f;
        __builtin_amdgcn_s_setprio(1);
        #pragma unroll
        for (int ds = 0; ds < 4; ++ds)
            s = MFMA3216(kA[ds], qB[ds], s);
        __builtin_amdgcn_s_setprio(0);

        // ---- P^T = exp2(S^T) ----
        #pragma unroll
        for (int r = 0; r < 16; ++r) {
            const float e = __builtin_amdgcn_exp2f(s[r]);
#if !LP_FDOT2
            (r & 2) ? ((r & 1) ? (lp3 += e) : (lp2 += e))
                    : ((r & 1) ? (lp1 += e) : (lp0 += e));
#endif
            s[r] = e;
        }

        // ---- pack to PV B-frags [idx=q][k=hi*8+j] per 16-k slice ----
        half8 pB[2];
        int PW[2][4];
        #pragma unroll
        for (int ks = 0; ks < 2; ++ks) {
            int P0 = __builtin_bit_cast(int, __builtin_amdgcn_cvt_pkrtz(s[ks * 8 + 0], s[ks * 8 + 1]));
            int P1 = __builtin_bit_cast(int, __builtin_amdgcn_cvt_pkrtz(s[ks * 8 + 2], s[ks * 8 + 3]));
            int P2 = __builtin_bit_cast(int, __builtin_amdgcn_cvt_pkrtz(s[ks * 8 + 4], s[ks * 8 + 5]));
            int P3 = __builtin_bit_cast(int, __builtin_amdgcn_cvt_pkrtz(s[ks * 8 + 6], s[ks * 8 + 7]));
            half_swap(P0, P2, hi);
            half_swap(P1, P3, hi);
            PW[ks][0] = P0; PW[ks][1] = P1; PW[ks][2] = P2; PW[ks][3] = P3;
            const intx4 w = {P0, P1, P2, P3};
            pB[ks] = __builtin_bit_cast(half8, w);
        }

        // ---- O^T += V^T P^T over wave's 32-k band ----
        __builtin_amdgcn_s_setprio(1);
        #pragma unroll
        for (int db = 0; db < 2; ++db)
            #pragma unroll
            for (int ks = 0; ks < 2; ++ks)
                O[db] = MFMA3216(vA[db * 2 + ks], pB[ks], O[db]);
        __builtin_amdgcn_s_setprio(0);

#if LP_FDOT2
        // ---- lp row-sum from packed P (MFMA pipe busy window) ----
        #pragma unroll
        for (int ks = 0; ks < 2; ++ks) {
            lp0 = __builtin_amdgcn_fdot2(__builtin_bit_cast(half2v, PW[ks][0]), one2, lp0, false);
            lp1 = __builtin_amdgcn_fdot2(__builtin_bit_cast(half2v, PW[ks][1]), one2, lp1, false);
            lp0 = __builtin_amdgcn_fdot2(__builtin_bit_cast(half2v, PW[ks][2]), one2, lp0, false);
            lp1 = __builtin_amdgcn_fdot2(__builtin_bit_cast(half2v, PW[ks][3]), one2, lp1, false);
        }
#endif
    }

    // ---- epilogue: 2-way k-band reduce + softmax normalize, 128 q rows ----
    float (*R)[132] = (float(*)[132])smem;            // [64 d][128 q(+4)] f32
    float* Lred = (float*)(smem + 33792);             // [2][128] f32

#if LP_FDOT2
    float lp = lp0 + lp1;
#else
    float lp = (lp0 + lp1) + (lp2 + lp3);
#endif
    lp += __shfl_xor(lp, 32, 64);                     // combine hi/lo (same q)
    const int qg = qb * 32 + l31;
    if (lane < 32) Lred[kb * 128 + qg] = lp;
    if (kb == 1) {
        #pragma unroll
        for (int db = 0; db < 2; ++db)
            #pragma unroll
            for (int r = 0; r < 16; ++r) {
                const int d = db * 32 + (r & 3) + 8 * (r >> 2) + 4 * hi;
                R[d][qg] = O[db][r];
            }
    }
    __syncthreads();
    if (kb == 0) {
        const float il = 1.0f / (Lred[qg] + Lred[128 + qg]);
        #pragma unroll
        for (int db = 0; db < 2; ++db)
            #pragma unroll
            for (int r = 0; r < 16; ++r) {
                const int d = db * 32 + (r & 3) + 8 * (r >> 2) + 4 * hi;
                O[db][r] = (O[db][r] + R[d][qg]) * il;
            }
    }
    __syncthreads();
    __half (*F)[72] = (__half(*)[72])smem;            // [128 q][64 d] f16
    if (kb == 0) {
        #pragma unroll
        for (int db = 0; db < 2; ++db)
            #pragma unroll
            for (int t = 0; t < 4; ++t) {
                half4 hv;
                #pragma unroll
                for (int r = 0; r < 4; ++r) hv[r] = (_Float16)O[db][t * 4 + r];
                *(half4*)&F[qg][db * 32 + t * 8 + hi * 4] = hv;
            }
    }
    __syncthreads();

    const int b = bh >> 4, h = bh & 15;
    const int qrow = tid >> 2, dseg = (tid & 3) * 16;
    __half* dstp = &attf[(((size_t)(b * S_ + q0 + qrow)) << 10) + h * DH_ + dseg];
    *(half8*)&dstp[0] = *(const half8*)&F[qrow][dseg];
    *(half8*)&dstp[8] = *(const half8*)&F[qrow][dseg + 8];
}

extern "C" void kernel_launch(void* const* d_in, const int* in_sizes, int n_in,
                              void* d_out, int out_size, void* d_ws, size_t ws_size,
                              hipStream_t stream) {
    const float* q  = (const float*)d_in[0];
    const float* k  = (const float*)d_in[1];
    const float* v  = (const float*)d_in[2];
    const float* Wq = (const float*)d_in[3];
    const float* bq = (const float*)d_in[4];
    const float* Wk = (const float*)d_in[5];
    const float* bk = (const float*)d_in[6];
    const float* Wv = (const float*)d_in[7];
    const float* bv = (const float*)d_in[8];
    const float* Wo = (const float*)d_in[9];
    const float* bo = (const float*)d_in[10];
    float* out = (float*)d_out;

    __half* ws = (__half*)d_ws;
    const size_t NE = (size_t)B_ * S_ * D_;     // 4,194,304
    __half* qf   = ws;
    __half* kf   = ws + NE;
    __half* vf   = ws + 2 * NE;
    __half* qhf  = ws + 3 * NE;
    __half* khf  = ws + 4 * NE;
    __half* vht  = ws + 5 * NE;
    __half* attf = ws + 6 * NE;
    __half* Wtq  = ws + 7 * NE;
    __half* Wtk  = Wtq + (size_t)D_ * D_;
    __half* Wtv  = Wtk + (size_t)D_ * D_;
    __half* Wto  = Wtv + (size_t)D_ * D_;

    const dim3 blk(256);
    prep<<<dim3((unsigned)(NE / 8 / 256), 1, 4), blk, 0, stream>>>(
        q, k, v, qf, kf, vf, Wq, Wk, Wv, Wo, Wtq, Wtk, Wtv, Wto);

    gemm_proj<<<dim3(D_ / 128, (B_ * S_) / 128, 3), blk, 0, stream>>>(
        qf, kf, vf, Wtq, Wtk, Wtv, bq, bk, bv, qhf, khf, vht);

    attn_f16<<<dim3(S_ / 128, B_ * H_), dim3(512), 0, stream>>>(qhf, khf, vht, attf);

    gemm_final<<<dim3(D_ / 128, (B_ * S_) / 128), blk, 0, stream>>>(attf, Wto, bo, out);
}

// Round 10
// 223.988 us; speedup vs baseline: 1.3354x; 1.3354x over previous
//
#include <hip/hip_runtime.h>
#include <hip/hip_fp16.h>
#include <cstddef>

// ---------------------------------------------------------------------------
// CrossAttention, f16 MFMA, round 18.
//   B=2, Sq=Sk=2048, D=1024, H=16, Dh=64
// r17 post-mortem: direct-global frag loads = TA gather (32 lines/inst),
// 128us. LDS staging IS the coalescing transform. Revert to r16 base.
// r16 analysis: attn chain/latency-bound (DS 55%, VALU 37%, MFMA 30%, no
// pipe saturated; 3500cyc/tile vs ~300 issue). Per-CU totals are tiling-
// invariant; per-WAVE chain is not. r18 attn: 1024 thr, 16 waves = 4 kb x
// 4 qb, QBLK=128, KVBLK=128, single-buffered LDS (K[128][72] + V0/V1
// [64][72]): per-wave MFMA/exp/DS-reads per k HALVED, barriers per 128k
// 4->2, per-CU DS volume unchanged. Epilogue: 4-way kb reduce, 3 rounds
// through R[128][68] f32 with b128 stores. Regs ~100 -> default cap 128.
// gemm kernels: r16 global_load_lds m97 structure (best). XCD swizzles kept.
// Layouts (32x32x16): A/B [idx=lane&31][k=(lane>>5)*8+j];
//   C/D col=lane&31, row=(reg&3)+8*(reg>>2)+4*(lane>>5)  [m74/m101].
// P repack: P0=pk(s0,s1) P1=pk(s2,s3) P2=pk(s4,s5) P3=pk(s6,s7);
//   swap(P0,P2), swap(P1,P3) -> B-frag words [P0,P1,P2,P3]. (r13-verified)
// ---------------------------------------------------------------------------

#define B_   2
#define S_   2048
#define D_   1024
#define H_   16
#define DH_  64

typedef _Float16 half8 __attribute__((ext_vector_type(8)));
typedef _Float16 half4 __attribute__((ext_vector_type(4)));
typedef _Float16 half2v __attribute__((ext_vector_type(2)));
typedef float floatx4 __attribute__((ext_vector_type(4)));
typedef float floatx16 __attribute__((ext_vector_type(16)));
typedef int intx4 __attribute__((ext_vector_type(4)));

#define MFMA32(a, b, c) __builtin_amdgcn_mfma_f32_16x16x32_f16((a), (b), (c), 0, 0, 0)
#define MFMA3216(a, b, c) __builtin_amdgcn_mfma_f32_32x32x16_f16((a), (b), (c), 0, 0, 0)

#if __has_builtin(__builtin_amdgcn_fdot2)
#define LP_FDOT2 1
#else
#define LP_FDOT2 0
#endif

#define GLD_AS(p) ((const __attribute__((address_space(1))) void*)(p))
#define LDS_AS(p) ((__attribute__((address_space(3))) void*)(p))

// exchange: newA = {A.lo32, B.lo32}, newB = {A.hi32, B.hi32}
__device__ __forceinline__ void half_swap(int& a, int& b, const int hi) {
#if __has_builtin(__builtin_amdgcn_permlane32_swap)
    (void)hi;
    auto r = __builtin_amdgcn_permlane32_swap(a, b, false, false);
    a = r[0]; b = r[1];
#else
    const int ax = __shfl_xor(a, 32, 64), bx = __shfl_xor(b, 32, 64);
    const int na = hi ? bx : a;
    b = hi ? b : ax;
    a = na;
#endif
}

// ---- fused: fp32->f16 cvt for q/k/v (z<3) + W transpose x4 (z==3) ----
__global__ __launch_bounds__(256) void prep(
    const float* __restrict__ q, const float* __restrict__ k,
    const float* __restrict__ v,
    __half* __restrict__ qf, __half* __restrict__ kf, __half* __restrict__ vf,
    const float* __restrict__ Wq, const float* __restrict__ Wk,
    const float* __restrict__ Wv, const float* __restrict__ Wo,
    __half* __restrict__ Wtq, __half* __restrict__ Wtk,
    __half* __restrict__ Wtv, __half* __restrict__ Wto)
{
    __shared__ __align__(16) __half T[64][72];
    const int tid = threadIdx.x;
    const int z = blockIdx.z;
    if (z < 3) {
        const float* srcs[3] = {q, k, v};
        __half* dsts[3] = {qf, kf, vf};
        const int i = blockIdx.x * 256 + tid;
        const float4* s = (const float4*)srcs[z];
        const float4 a = s[2 * i], b = s[2 * i + 1];
        half8 h;
        h[0] = (_Float16)a.x; h[1] = (_Float16)a.y; h[2] = (_Float16)a.z; h[3] = (_Float16)a.w;
        h[4] = (_Float16)b.x; h[5] = (_Float16)b.y; h[6] = (_Float16)b.z; h[7] = (_Float16)b.w;
        *(half8*)&dsts[z][(size_t)i * 8] = h;
        return;
    }
    if (blockIdx.x >= 256) return;
    const float* Ws[4] = {Wq, Wk, Wv, Wo};
    __half* Wts[4] = {Wtq, Wtk, Wtv, Wto};
    const int n0 = (blockIdx.x & 15) * 64, k0 = (blockIdx.x >> 4) * 64;
    for (int w = 0; w < 4; ++w) {
        const float* W = Ws[w];
        __half* Wt = Wts[w];
        #pragma unroll
        for (int p = 0; p < 4; ++p) {
            const int c = tid + p * 256;
            const int kr = c >> 4, nc = (c & 15) * 4;
            const float4 a = *(const float4*)&W[(size_t)(k0 + kr) * D_ + n0 + nc];
            T[nc + 0][kr] = __float2half(a.x);
            T[nc + 1][kr] = __float2half(a.y);
            T[nc + 2][kr] = __float2half(a.z);
            T[nc + 3][kr] = __float2half(a.w);
        }
        __syncthreads();
        #pragma unroll
        for (int p = 0; p < 2; ++p) {
            const int c = tid + p * 256;
            const int nr = c >> 3, kc = (c & 7) * 8;
            *(half8*)&Wt[(size_t)(n0 + nr) * D_ + k0 + kc] = *(const half8*)&T[nr][kc];
        }
        __syncthreads();
    }
}

// ---- 128x128 f16 GEMM core, m97-style global_load_lds staging (r16) ----
__device__ __forceinline__ void gemm_core(
    const __half* __restrict__ A, const __half* __restrict__ Bt,
    const float* __restrict__ bias, void* __restrict__ dst,
    const int mode, const float oscale, const int m0, const int n0)
{
    __shared__ __align__(16) char gsm[34816];
    __half* Asl = (__half*)gsm;            // [128][64] linear
    __half* Bsl = (__half*)(gsm + 16384);  // [128][64] linear

    const int tid = threadIdx.x;
    const int lane = tid & 63, wv = tid >> 6;
    const int quad = lane >> 4, lr = lane & 15;
    const int wm0 = (wv >> 1) * 64, wn0 = (wv & 1) * 64;

    floatx4 acc[4][4];
    #pragma unroll
    for (int i = 0; i < 4; ++i)
        #pragma unroll
        for (int j = 0; j < 4; ++j)
            acc[i][j] = (floatx4){0.f, 0.f, 0.f, 0.f};

    const int rowb = wv * 32 + (lane >> 3);
    const int colb = (lane & 7) * 8;
    const __half* gA = A  + (size_t)(m0 + rowb) * D_ + colb;
    const __half* gB = Bt + (size_t)(n0 + rowb) * D_ + colb;

    for (int k0 = 0; k0 < D_; k0 += 64) {
        __syncthreads();                  // prior compute's LDS reads done
        #pragma unroll
        for (int p = 0; p < 4; ++p) {
            __builtin_amdgcn_global_load_lds(
                GLD_AS(gA + (size_t)p * 8 * D_),
                LDS_AS(gsm + (wv * 4 + p) * 1024), 16, 0, 0);
            __builtin_amdgcn_global_load_lds(
                GLD_AS(gB + (size_t)p * 8 * D_),
                LDS_AS(gsm + 16384 + (wv * 4 + p) * 1024), 16, 0, 0);
        }
        gA += 64; gB += 64;
        __syncthreads();                  // staged tile visible (vmcnt drained)

        __builtin_amdgcn_s_setprio(1);
        #pragma unroll
        for (int ks = 0; ks < 2; ++ks) {
            const int ko = quad * 8 + ks * 32;
            half8 af[4], bf[4];
            #pragma unroll
            for (int i = 0; i < 4; ++i)
                af[i] = *(const half8*)&Asl[(wm0 + i * 16 + lr) * 64 + ko];
            #pragma unroll
            for (int j = 0; j < 4; ++j)
                bf[j] = *(const half8*)&Bsl[(wn0 + j * 16 + lr) * 64 + ko];
            #pragma unroll
            for (int i = 0; i < 4; ++i)
                #pragma unroll
                for (int j = 0; j < 4; ++j)
                    acc[i][j] = MFMA32(af[i], bf[j], acc[i][j]);
        }
        __builtin_amdgcn_s_setprio(0);
    }

    if (mode == 1) {
        float* out = (float*)dst;
        #pragma unroll
        for (int i = 0; i < 4; ++i) {
            #pragma unroll
            for (int j = 0; j < 4; ++j) {
                const int col = n0 + wn0 + j * 16 + lr;
                const float bval = bias[col];
                #pragma unroll
                for (int r = 0; r < 4; ++r) {
                    const int m = m0 + wm0 + i * 16 + quad * 4 + r;
                    out[(size_t)m * D_ + col] = acc[i][j][r] + bval;
                }
            }
        }
        return;
    }

    // ---- LDS transpose epilogue (modes 0 and 2) ----
    __syncthreads();                      // all waves' staging reads done
    __half (*Ct)[136] = (__half(*)[136])gsm;
    #pragma unroll
    for (int i = 0; i < 4; ++i) {
        #pragma unroll
        for (int j = 0; j < 4; ++j) {
            const int nl = wn0 + j * 16 + lr;
            const float bval = bias[n0 + nl];
            #pragma unroll
            for (int r = 0; r < 4; ++r) {
                const int ml = wm0 + i * 16 + quad * 4 + r;
                const _Float16 hv = (_Float16)((acc[i][j][r] + bval) * oscale);
                if (mode == 0) Ct[ml][nl] = hv;
                else           Ct[nl][ml] = hv;
            }
        }
    }
    __syncthreads();
    __half* oh = (__half*)dst;
    #pragma unroll
    for (int p = 0; p < 8; ++p) {
        const int row = (tid >> 4) + p * 16;
        const int cs  = (tid & 15) * 8;
        const half8 vls = *(const half8*)&Ct[row][cs];
        if (mode == 0) {
            const int m = m0 + row, col = n0 + cs;
            const int b = m >> 11, s = m & (S_ - 1);
            const int h = col >> 6, d = col & 63;
            *(half8*)&oh[(((size_t)(b * H_ + h) * S_ + s) << 6) + d] = vls;
        } else {
            const int col = n0 + row, m = m0 + cs;
            const int b = m >> 11, s = m & (S_ - 1);
            const int h = col >> 6, d = col & 63;
            *(half8*)&oh[((size_t)(b * H_ + h) * DH_ + d) * S_ + s] = vls;
        }
    }
}

// z=0: Q (scatter, *0.125*log2e for exp2 softmax), z=1: K, z=2: V (transposed)
// XCD swizzle: grid (8,32,3)=768 blocks, 96/XCD contiguous (bijective).
__global__ __launch_bounds__(256) void gemm_proj(
    const __half* __restrict__ qf, const __half* __restrict__ kf,
    const __half* __restrict__ vf,
    const __half* __restrict__ Wtq, const __half* __restrict__ Wtk,
    const __half* __restrict__ Wtv,
    const float* __restrict__ bq, const float* __restrict__ bk,
    const float* __restrict__ bv,
    __half* __restrict__ qhf, __half* __restrict__ khf, __half* __restrict__ vht)
{
    const int flat = blockIdx.x + (blockIdx.y << 3) + (blockIdx.z << 8);
    const int wid = (flat & 7) * 96 + (flat >> 3);
    const int z = wid >> 8;
    const int rem = wid & 255;
    const int m0 = (rem >> 3) * 128, n0 = (rem & 7) * 128;

    const __half* As[3] = {qf, kf, vf};
    const __half* Bts[3] = {Wtq, Wtk, Wtv};
    const float* bs[3] = {bq, bk, bv};
    __half* ds[3] = {qhf, khf, vht};
    gemm_core(As[z], Bts[z], bs[z], ds[z], z == 2 ? 2 : 0,
              z == 0 ? 0.1803368801111244f : 1.0f, m0, n0);
}

// XCD swizzle: grid (8,32)=256 blocks, 32/XCD contiguous.
__global__ __launch_bounds__(256) void gemm_final(
    const __half* __restrict__ attf, const __half* __restrict__ Wto,
    const float* __restrict__ bo, float* __restrict__ out)
{
    const int flat = blockIdx.x + (blockIdx.y << 3);
    const int wid = (flat & 7) * 32 + (flat >> 3);
    const int m0 = (wid >> 3) * 128, n0 = (wid & 7) * 128;
    gemm_core(attf, Wto, bo, out, 1, 1.0f, m0, n0);
}

// ---- flash attention r18: 1024 thr, 16 waves = 4 kb x 4 qb, KVBLK=128 ----
// qhf/khf: [B,H,S,64] f16 (Q pre-scaled 0.125*log2e). vht: [B,H,64,S].
// LDS single-buffer 36864B: K[128][72] @0 (18432), V0[64][72] @18432,
// V1[64][72] @27648 (cols 0-63 / 64-127 of the 128-k tile).
// Per wave per 128k tile: 4 QK MFMA + 16 exp2 + repack + 4 PV MFMA +
// 8 fdot2; 8 DS reads; 2 barriers. Epilogue: 4-way kb reduce via
// R[128][68] f32 (b128 stores), 3 rounds; Lred[4][128] @34816.
// XCD swizzle: grid (16,32)=512 blocks, 64/XCD.
__global__ __launch_bounds__(1024) void attn_f16(
    const __half* __restrict__ qhf, const __half* __restrict__ khf,
    const __half* __restrict__ vht, __half* __restrict__ attf)
{
    __shared__ __align__(16) char smem[36864];
    __half (*Ks)[72] = (__half(*)[72])smem;              // [128 k][64 d]
    __half (*V0)[72] = (__half(*)[72])(smem + 18432);    // [64 d][64 s]
    __half (*V1)[72] = (__half(*)[72])(smem + 27648);    // [64 d][64 s]

    const int tid = threadIdx.x;
    const int lane = tid & 63, wv = tid >> 6;
    const int l31 = lane & 31, hi = lane >> 5;
    const int kb = wv >> 2, qb = wv & 3;                 // 4 k-bands x 4 q-bands
    const int flat = blockIdx.x + (blockIdx.y << 4);
    const int wid = ((flat & 7) << 6) + (flat >> 3);
    const int bh = wid >> 4;
    const int q0 = (wid & 15) * 128;
    const size_t hbase = (size_t)bh * S_ * DH_;

    // ---- Q B-frags [idx=q=l31][k(d)=hi*8+j] per 16-d slice, from global ----
    half8 qB[4];
    #pragma unroll
    for (int ds = 0; ds < 4; ++ds)
        qB[ds] = *(const half8*)&qhf[hbase
            + (size_t)(q0 + qb * 32 + l31) * DH_ + ds * 16 + hi * 8];

    float lp0 = 0.f, lp1 = 0.f;
#if !LP_FDOT2
    float lp2 = 0.f, lp3 = 0.f;
#endif
    floatx16 O[2];
    #pragma unroll
    for (int i = 0; i < 16; ++i) { O[0][i] = 0.f; O[1][i] = 0.f; }

    // ---- staging mapping (1024 thr): one K + one V half8 per thread ----
    const int krow = tid >> 3, kseg = (tid & 7) * 8;     // K: [128][64]
    const int vrow = tid >> 4, vcol = (tid & 15) * 8;    // V: [64][128]
    __half* vdst = (vcol < 64) ? &V0[vrow][vcol] : &V1[vrow][vcol - 64];
    const __half* kg = khf + hbase + (size_t)krow * DH_ + kseg;   // += 128*DH_
    const __half* vg = vht + hbase + (size_t)vrow * S_ + vcol;    // += 128

    // ---- prefetch tile 0 into registers ----
    half8 pk = *(const half8*)kg;
    half8 pv = *(const half8*)vg;

    const half2v one2 = {(_Float16)1.0f, (_Float16)1.0f};
    const int vband = (kb & 1) * 32;                     // col base within V0/V1

    for (int kt = 0; kt < S_; kt += 128) {
        __syncthreads();                  // prev tile's LDS reads done
        *(half8*)&Ks[krow][kseg] = pk;
        *(half8*)vdst = pv;
        if (kt + 128 < S_) {              // issue t+1 loads; fly during compute
            kg += 128 * DH_; vg += 128;
            pk = *(const half8*)kg;
            pv = *(const half8*)vg;
        }
        __syncthreads();                  // staged tile visible

        // ---- S^T = K Q^T : 32k (band kb) x 32q (band qb), K-dim = d ----
        floatx16 s;
        #pragma unroll
        for (int i = 0; i < 16; ++i) s[i] = 0.f;
        __builtin_amdgcn_s_setprio(1);
        #pragma unroll
        for (int ds = 0; ds < 4; ++ds) {
            const half8 aK = *(const half8*)&Ks[kb * 32 + l31][ds * 16 + hi * 8];
            s = MFMA3216(aK, qB[ds], s);
        }
        __builtin_amdgcn_s_setprio(0);

        // ---- P^T = exp2(S^T) ----
        #pragma unroll
        for (int r = 0; r < 16; ++r) {
            const float e = __builtin_amdgcn_exp2f(s[r]);
#if !LP_FDOT2
            (r & 2) ? ((r & 1) ? (lp3 += e) : (lp2 += e))
                    : ((r & 1) ? (lp1 += e) : (lp0 += e));
#endif
            s[r] = e;
        }

        // ---- pack to PV B-frags [idx=q][k=hi*8+j] per 16-k slice ----
        half8 pB[2];
        int PW[2][4];
        #pragma unroll
        for (int ks = 0; ks < 2; ++ks) {
            int P0 = __builtin_bit_cast(int, __builtin_amdgcn_cvt_pkrtz(s[ks * 8 + 0], s[ks * 8 + 1]));
            int P1 = __builtin_bit_cast(int, __builtin_amdgcn_cvt_pkrtz(s[ks * 8 + 2], s[ks * 8 + 3]));
            int P2 = __builtin_bit_cast(int, __builtin_amdgcn_cvt_pkrtz(s[ks * 8 + 4], s[ks * 8 + 5]));
            int P3 = __builtin_bit_cast(int, __builtin_amdgcn_cvt_pkrtz(s[ks * 8 + 6], s[ks * 8 + 7]));
            half_swap(P0, P2, hi);
            half_swap(P1, P3, hi);
            PW[ks][0] = P0; PW[ks][1] = P1; PW[ks][2] = P2; PW[ks][3] = P3;
            const intx4 w = {P0, P1, P2, P3};
            pB[ks] = __builtin_bit_cast(half8, w);
        }

        // ---- O^T += V^T P^T over wave's 32-k band ----
        __half (*Vsub)[72] = (kb < 2) ? V0 : V1;
        __builtin_amdgcn_s_setprio(1);
        #pragma unroll
        for (int db = 0; db < 2; ++db)
            #pragma unroll
            for (int ks = 0; ks < 2; ++ks) {
                const half8 aV = *(const half8*)&Vsub[db * 32 + l31][vband + ks * 16 + hi * 8];
                O[db] = MFMA3216(aV, pB[ks], O[db]);
            }
        __builtin_amdgcn_s_setprio(0);

#if LP_FDOT2
        // ---- lp row-sum from packed P (MFMA pipe busy window) ----
        #pragma unroll
        for (int ks = 0; ks < 2; ++ks) {
            lp0 = __builtin_amdgcn_fdot2(__builtin_bit_cast(half2v, PW[ks][0]), one2, lp0, false);
            lp1 = __builtin_amdgcn_fdot2(__builtin_bit_cast(half2v, PW[ks][1]), one2, lp1, false);
            lp0 = __builtin_amdgcn_fdot2(__builtin_bit_cast(half2v, PW[ks][2]), one2, lp0, false);
            lp1 = __builtin_amdgcn_fdot2(__builtin_bit_cast(half2v, PW[ks][3]), one2, lp1, false);
        }
#endif
    }

    // ---- epilogue: 4-way kb reduce + softmax normalize, 128 q rows ----
    __syncthreads();                                  // last tile reads done
    float (*R)[68] = (float(*)[68])smem;              // [128 q][68 d] f32
    float* Lred = (float*)(smem + 34816);             // [4][128] f32

#if LP_FDOT2
    float lp = lp0 + lp1;
#else
    float lp = (lp0 + lp1) + (lp2 + lp3);
#endif
    lp += __shfl_xor(lp, 32, 64);                     // combine hi/lo (same q)
    const int qg = qb * 32 + l31;
    if (lane < 32) Lred[kb * 128 + qg] = lp;

    // 3 rounds: kb==r dumps O into R, kb==0 accumulates
    #pragma unroll
    for (int r = 1; r < 4; ++r) {
        if (kb == r) {
            #pragma unroll
            for (int db = 0; db < 2; ++db)
                #pragma unroll
                for (int t = 0; t < 4; ++t) {
                    const floatx4 v4 = {O[db][t * 4 + 0], O[db][t * 4 + 1],
                                        O[db][t * 4 + 2], O[db][t * 4 + 3]};
                    *(floatx4*)&R[qg][db * 32 + t * 8 + hi * 4] = v4;
                }
        }
        __syncthreads();
        if (kb == 0) {
            #pragma unroll
            for (int db = 0; db < 2; ++db)
                #pragma unroll
                for (int t = 0; t < 4; ++t) {
                    const floatx4 v4 = *(const floatx4*)&R[qg][db * 32 + t * 8 + hi * 4];
                    #pragma unroll
                    for (int j = 0; j < 4; ++j) O[db][t * 4 + j] += v4[j];
                }
        }
        __syncthreads();
    }

    __half (*F)[72] = (__half(*)[72])smem;            // [128 q][64 d] f16
    if (kb == 0) {
        const float il = 1.0f / (Lred[qg] + Lred[128 + qg]
                               + Lred[256 + qg] + Lred[384 + qg]);
        #pragma unroll
        for (int db = 0; db < 2; ++db)
            #pragma unroll
            for (int t = 0; t < 4; ++t) {
                half4 hv;
                #pragma unroll
                for (int j = 0; j < 4; ++j) hv[j] = (_Float16)(O[db][t * 4 + j] * il);
                *(half4*)&F[qg][db * 32 + t * 8 + hi * 4] = hv;
            }
    }
    __syncthreads();

    const int b = bh >> 4, h = bh & 15;
    const int qrow = tid >> 3, dseg = (tid & 7) * 8;
    *(half8*)&attf[(((size_t)(b * S_ + q0 + qrow)) << 10) + h * DH_ + dseg]
        = *(const half8*)&F[qrow][dseg];
}

extern "C" void kernel_launch(void* const* d_in, const int* in_sizes, int n_in,
                              void* d_out, int out_size, void* d_ws, size_t ws_size,
                              hipStream_t stream) {
    const float* q  = (const float*)d_in[0];
    const float* k  = (const float*)d_in[1];
    const float* v  = (const float*)d_in[2];
    const float* Wq = (const float*)d_in[3];
    const float* bq = (const float*)d_in[4];
    const float* Wk = (const float*)d_in[5];
    const float* bk = (const float*)d_in[6];
    const float* Wv = (const float*)d_in[7];
    const float* bv = (const float*)d_in[8];
    const float* Wo = (const float*)d_in[9];
    const float* bo = (const float*)d_in[10];
    float* out = (float*)d_out;

    __half* ws = (__half*)d_ws;
    const size_t NE = (size_t)B_ * S_ * D_;     // 4,194,304
    __half* qf   = ws;
    __half* kf   = ws + NE;
    __half* vf   = ws + 2 * NE;
    __half* qhf  = ws + 3 * NE;
    __half* khf  = ws + 4 * NE;
    __half* vht  = ws + 5 * NE;
    __half* attf = ws + 6 * NE;
    __half* Wtq  = ws + 7 * NE;
    __half* Wtk  = Wtq + (size_t)D_ * D_;
    __half* Wtv  = Wtk + (size_t)D_ * D_;
    __half* Wto  = Wtv + (size_t)D_ * D_;

    const dim3 blk(256);
    prep<<<dim3((unsigned)(NE / 8 / 256), 1, 4), blk, 0, stream>>>(
        q, k, v, qf, kf, vf, Wq, Wk, Wv, Wo, Wtq, Wtk, Wtv, Wto);

    gemm_proj<<<dim3(D_ / 128, (B_ * S_) / 128, 3), blk, 0, stream>>>(
        qf, kf, vf, Wtq, Wtk, Wtv, bq, bk, bv, qhf, khf, vht);

    attn_f16<<<dim3(S_ / 128, B_ * H_), dim3(1024), 0, stream>>>(qhf, khf, vht, attf);

    gemm_final<<<dim3(D_ / 128, (B_ * S_) / 128), blk, 0, stream>>>(attf, Wto, bo, out);
}